// Round 1
// baseline (973.384 us; speedup 1.0000x reference)
//
#include <hip/hip_runtime.h>
#include <math.h>

#define NHEADS 8
#define C 512
#define HW 1024
#define HD 64

// ---------------- GroupNorm: one block per (batch, group) ----------------
// group = 16 channels x 1024 spatial = 16384 floats. Keep all data in regs
// (16 float4/thread), block-reduce sum/sumsq, normalize, write xn.
__global__ __launch_bounds__(256) void gn_kernel(const float* __restrict__ x,
                                                 const float* __restrict__ gamma,
                                                 const float* __restrict__ beta,
                                                 float* __restrict__ xn) {
  int b = blockIdx.x >> 5, g = blockIdx.x & 31;
  const size_t base = ((size_t)b * C + (size_t)g * 16) * HW;
  const float4* xp = (const float4*)(x + base);
  float4* xnp = (float4*)(xn + base);
  int tid = threadIdx.x;

  float s = 0.f, ss = 0.f;
  float4 v[16];
#pragma unroll
  for (int it = 0; it < 16; it++) {
    v[it] = xp[tid + it * 256];
    s += v[it].x + v[it].y + v[it].z + v[it].w;
    ss += v[it].x * v[it].x + v[it].y * v[it].y + v[it].z * v[it].z + v[it].w * v[it].w;
  }
#pragma unroll
  for (int off = 32; off > 0; off >>= 1) {
    s += __shfl_down(s, off);
    ss += __shfl_down(ss, off);
  }
  __shared__ float red[8];
  __shared__ float mi[2];
  int wid = tid >> 6;
  if ((tid & 63) == 0) { red[wid] = s; red[4 + wid] = ss; }
  __syncthreads();
  if (tid == 0) {
    float S = red[0] + red[1] + red[2] + red[3];
    float SS = red[4] + red[5] + red[6] + red[7];
    float mean = S * (1.f / 16384.f);
    float var = SS * (1.f / 16384.f) - mean * mean;
    mi[0] = mean;
    mi[1] = rsqrtf(var + 1e-5f);
  }
  __syncthreads();
  float mean = mi[0], inv = mi[1];
#pragma unroll
  for (int it = 0; it < 16; it++) {
    int c = g * 16 + it;  // each it covers exactly one channel (256 float4 = 1024 floats)
    float ga = gamma[c] * inv;
    float be = beta[c] - mean * ga;
    float4 o;
    o.x = v[it].x * ga + be;
    o.y = v[it].y * ga + be;
    o.z = v[it].z * ga + be;
    o.w = v[it].w * ga + be;
    xnp[tid + it * 256] = o;
  }
}

// ---------------- 1x1 conv as GEMM: Y[b][o][j] = sum_c W[o][c] X[b][c][j] ----
// 64x64 tile, K-step 16, 256 threads, 4x4 micro-tile per thread.
template <bool RES>
__global__ __launch_bounds__(256) void conv1x1_kernel(const float* __restrict__ W,
                                                      const float* __restrict__ bias,
                                                      const float* __restrict__ X,
                                                      const float* __restrict__ R,
                                                      float* __restrict__ Y, int OC) {
  int jt = blockIdx.x;  // j tile (16 of 64)
  int ot = blockIdx.y;  // o tile (OC/64)
  int b = blockIdx.z;
  int tid = threadIdx.x;
  int tx = tid & 15;   // j direction
  int ty = tid >> 4;   // o direction

  __shared__ float Ws[16][64];  // [k][o]
  __shared__ float Xs[16][64];  // [k][j]
  float acc[4][4] = {};

  const float* Wp = W + (size_t)(ot * 64) * 512;
  const float* Xp = X + ((size_t)b * C) * HW + jt * 64;

  for (int kk = 0; kk < 512; kk += 16) {
    __syncthreads();
    {
      int e = tid * 4;
      int o = e >> 4;  // row of W tile
      int k = e & 15;
      float4 wv = *(const float4*)&Wp[(size_t)o * 512 + kk + k];
      Ws[k + 0][o] = wv.x;
      Ws[k + 1][o] = wv.y;
      Ws[k + 2][o] = wv.z;
      Ws[k + 3][o] = wv.w;
    }
    {
      int e = tid * 4;
      int k = e >> 6;
      int j = e & 63;
      *(float4*)&Xs[k][j] = *(const float4*)&Xp[(size_t)(kk + k) * HW + j];
    }
    __syncthreads();
#pragma unroll
    for (int k = 0; k < 16; k++) {
      float wv[4], xv[4];
      *(float4*)wv = *(const float4*)&Ws[k][ty * 4];
      *(float4*)xv = *(const float4*)&Xs[k][tx * 4];
#pragma unroll
      for (int a = 0; a < 4; a++)
#pragma unroll
        for (int c2 = 0; c2 < 4; c2++) acc[a][c2] += wv[a] * xv[c2];
    }
  }

  int o0 = ot * 64 + ty * 4;
  int j0g = jt * 64 + tx * 4;
#pragma unroll
  for (int a = 0; a < 4; a++) {
    int o = o0 + a;
    float bs = bias[o];
    size_t idx = ((size_t)b * OC + o) * HW + j0g;
    float4 r;
    r.x = acc[a][0] + bs;
    r.y = acc[a][1] + bs;
    r.z = acc[a][2] + bs;
    r.w = acc[a][3] + bs;
    if (RES) {
      float4 res = *(const float4*)&R[idx];
      r.x += res.x; r.y += res.y; r.z += res.z; r.w += res.w;
    }
    *(float4*)&Y[idx] = r;
  }
}

// ---------------- Flash attention: one thread per query position -----------
// qkv: [8][1536][1024]; head h uses channels h*64..h*64+63 of each of q/k/v.
// attn out written as [b][c][hw] so the out-projection is a plain GEMM.
__global__ __launch_bounds__(256) void attn_kernel(const float* __restrict__ qkv,
                                                   float* __restrict__ attn) {
  int bh = blockIdx.y;
  int b = bh >> 3, hh = bh & 7;
  int i = blockIdx.x * 256 + threadIdx.x;

  const float* qp = qkv + ((size_t)b * 1536 + hh * 64) * HW;
  const float* kp = qp + (size_t)C * HW;
  const float* vp = kp + (size_t)C * HW;

  float q[HD];
#pragma unroll
  for (int d = 0; d < HD; d++) q[d] = qp[(size_t)d * HW + i] * 0.125f;

  float m = -1e30f, l = 0.f;
  float acc[HD];
#pragma unroll
  for (int d = 0; d < HD; d++) acc[d] = 0.f;

  __shared__ float kt[64][HD];  // transposed: [jj][d] -> d-dim contiguous
  __shared__ float vt[64][HD];

  for (int j0 = 0; j0 < HW; j0 += 64) {
    __syncthreads();
#pragma unroll
    for (int it = 0; it < 4; it++) {
      int e = (threadIdx.x + it * 256) * 4;
      int d = e >> 6, jj = e & 63;
      float4 k4 = *(const float4*)&kp[(size_t)d * HW + j0 + jj];
      float4 v4 = *(const float4*)&vp[(size_t)d * HW + j0 + jj];
      kt[jj + 0][d] = k4.x; kt[jj + 1][d] = k4.y; kt[jj + 2][d] = k4.z; kt[jj + 3][d] = k4.w;
      vt[jj + 0][d] = v4.x; vt[jj + 1][d] = v4.y; vt[jj + 2][d] = v4.z; vt[jj + 3][d] = v4.w;
    }
    __syncthreads();
#pragma unroll 4
    for (int jj = 0; jj < 64; jj++) {
      float sc = 0.f;
#pragma unroll
      for (int d4 = 0; d4 < 16; d4++) {
        float4 k4 = *(const float4*)&kt[jj][d4 * 4];
        sc += q[d4 * 4 + 0] * k4.x + q[d4 * 4 + 1] * k4.y +
              q[d4 * 4 + 2] * k4.z + q[d4 * 4 + 3] * k4.w;
      }
      if (sc > m) {
        float corr = __expf(m - sc);
        l *= corr;
#pragma unroll
        for (int d = 0; d < HD; d++) acc[d] *= corr;
        m = sc;
      }
      float p = __expf(sc - m);
      l += p;
#pragma unroll
      for (int d4 = 0; d4 < 16; d4++) {
        float4 v4 = *(const float4*)&vt[jj][d4 * 4];
        acc[d4 * 4 + 0] += p * v4.x;
        acc[d4 * 4 + 1] += p * v4.y;
        acc[d4 * 4 + 2] += p * v4.z;
        acc[d4 * 4 + 3] += p * v4.w;
      }
    }
  }

  float invl = 1.f / l;
  float* op = attn + ((size_t)b * C + hh * 64) * HW;
#pragma unroll
  for (int d = 0; d < HD; d++) op[(size_t)d * HW + i] = acc[d] * invl;
}

extern "C" void kernel_launch(void* const* d_in, const int* in_sizes, int n_in,
                              void* d_out, int out_size, void* d_ws, size_t ws_size,
                              hipStream_t stream) {
  const float* x = (const float*)d_in[0];
  const float* gamma = (const float*)d_in[1];
  const float* beta = (const float*)d_in[2];
  const float* w_qkv = (const float*)d_in[3];
  const float* b_qkv = (const float*)d_in[4];
  const float* w_out = (const float*)d_in[5];
  const float* b_out = (const float*)d_in[6];
  float* out = (float*)d_out;

  float* xn = (float*)d_ws;                 // [8][512][1024] f32; reused as attn-out
  float* qkv = xn + (size_t)8 * C * HW;     // [8][1536][1024] f32

  // 1. GroupNorm
  gn_kernel<<<dim3(256), 256, 0, stream>>>(x, gamma, beta, xn);
  // 2. QKV projection
  conv1x1_kernel<false><<<dim3(16, 24, 8), 256, 0, stream>>>(w_qkv, b_qkv, xn, nullptr, qkv, 3 * C);
  // 3. Attention (overwrites xn with attention output in [b][c][hw] layout)
  attn_kernel<<<dim3(4, 64), 256, 0, stream>>>(qkv, xn);
  // 4. Output projection + bias + residual
  conv1x1_kernel<true><<<dim3(16, 8, 8), 256, 0, stream>>>(w_out, b_out, xn, x, out, C);
}

// Round 3
// 415.111 us; speedup vs baseline: 2.3449x; 2.3449x over previous
//
#include <hip/hip_runtime.h>
#include <math.h>

#define NHEADS 8
#define C 512
#define HW 1024
#define HD 64

typedef __bf16 bf16x8 __attribute__((ext_vector_type(8)));
typedef __bf16 bf16x4 __attribute__((ext_vector_type(4)));
typedef float f32x4 __attribute__((ext_vector_type(4)));

// ---------------- GroupNorm: one block per (batch, group) ----------------
__global__ __launch_bounds__(256) void gn_kernel(const float* __restrict__ x,
                                                 const float* __restrict__ gamma,
                                                 const float* __restrict__ beta,
                                                 float* __restrict__ xn) {
  int b = blockIdx.x >> 5, g = blockIdx.x & 31;
  const size_t base = ((size_t)b * C + (size_t)g * 16) * HW;
  const float4* xp = (const float4*)(x + base);
  float4* xnp = (float4*)(xn + base);
  int tid = threadIdx.x;

  float s = 0.f, ss = 0.f;
  float4 v[16];
#pragma unroll
  for (int it = 0; it < 16; it++) {
    v[it] = xp[tid + it * 256];
    s += v[it].x + v[it].y + v[it].z + v[it].w;
    ss += v[it].x * v[it].x + v[it].y * v[it].y + v[it].z * v[it].z + v[it].w * v[it].w;
  }
#pragma unroll
  for (int off = 32; off > 0; off >>= 1) {
    s += __shfl_down(s, off);
    ss += __shfl_down(ss, off);
  }
  __shared__ float red[8];
  __shared__ float mi[2];
  int wid = tid >> 6;
  if ((tid & 63) == 0) { red[wid] = s; red[4 + wid] = ss; }
  __syncthreads();
  if (tid == 0) {
    float S = red[0] + red[1] + red[2] + red[3];
    float SS = red[4] + red[5] + red[6] + red[7];
    float mean = S * (1.f / 16384.f);
    float var = SS * (1.f / 16384.f) - mean * mean;
    mi[0] = mean;
    mi[1] = rsqrtf(var + 1e-5f);
  }
  __syncthreads();
  float mean = mi[0], inv = mi[1];
#pragma unroll
  for (int it = 0; it < 16; it++) {
    int c = g * 16 + it;
    float ga = gamma[c] * inv;
    float be = beta[c] - mean * ga;
    float4 o;
    o.x = v[it].x * ga + be;
    o.y = v[it].y * ga + be;
    o.z = v[it].z * ga + be;
    o.w = v[it].w * ga + be;
    xnp[tid + it * 256] = o;
  }
}

// ---------------- 1x1 conv as GEMM ----------------
// MODE 0: Y fp32 + residual (out projection)
// MODE 1: QKV -> bf16 qT [bh][i][d], kT [bh][j][d], vN [bh][d][j]
template <int MODE>
__global__ __launch_bounds__(256) void conv1x1_kernel(const float* __restrict__ W,
                                                      const float* __restrict__ bias,
                                                      const float* __restrict__ X,
                                                      const float* __restrict__ R,
                                                      float* __restrict__ Y,
                                                      __bf16* __restrict__ qT,
                                                      __bf16* __restrict__ kT,
                                                      __bf16* __restrict__ vN,
                                                      int OC) {
  int jt = blockIdx.x;
  int ot = blockIdx.y;
  int b = blockIdx.z;
  int tid = threadIdx.x;
  int tx = tid & 15;
  int ty = tid >> 4;

  __shared__ float Ws[16][64];
  __shared__ float Xs[16][64];
  float acc[4][4] = {};

  const float* Wp = W + (size_t)(ot * 64) * 512;
  const float* Xp = X + ((size_t)b * C) * HW + jt * 64;

  for (int kk = 0; kk < 512; kk += 16) {
    __syncthreads();
    {
      int e = tid * 4;
      int o = e >> 4;
      int k = e & 15;
      float4 wv = *(const float4*)&Wp[(size_t)o * 512 + kk + k];
      Ws[k + 0][o] = wv.x;
      Ws[k + 1][o] = wv.y;
      Ws[k + 2][o] = wv.z;
      Ws[k + 3][o] = wv.w;
    }
    {
      int e = tid * 4;
      int k = e >> 6;
      int j = e & 63;
      *(float4*)&Xs[k][j] = *(const float4*)&Xp[(size_t)(kk + k) * HW + j];
    }
    __syncthreads();
#pragma unroll
    for (int k = 0; k < 16; k++) {
      float wv[4], xv[4];
      *(float4*)wv = *(const float4*)&Ws[k][ty * 4];
      *(float4*)xv = *(const float4*)&Xs[k][tx * 4];
#pragma unroll
      for (int a = 0; a < 4; a++)
#pragma unroll
        for (int c2 = 0; c2 < 4; c2++) acc[a][c2] += wv[a] * xv[c2];
    }
  }

  int o0 = ot * 64 + ty * 4;
  int j0g = jt * 64 + tx * 4;

  if (MODE == 0) {
#pragma unroll
    for (int a = 0; a < 4; a++) {
      int o = o0 + a;
      float bs = bias[o];
      size_t idx = ((size_t)b * OC + o) * HW + j0g;
      float4 r;
      r.x = acc[a][0] + bs;
      r.y = acc[a][1] + bs;
      r.z = acc[a][2] + bs;
      r.w = acc[a][3] + bs;
      float4 res = *(const float4*)&R[idx];
      r.x += res.x; r.y += res.y; r.z += res.z; r.w += res.w;
      *(float4*)&Y[idx] = r;
    }
  } else {
    int sec = o0 >> 9;          // 0=Q, 1=K, 2=V
    int oc = o0 & 511;
    int h = oc >> 6;
    int d0 = oc & 63;
    size_t headbase = (size_t)b * NHEADS + h;
    float bs[4];
#pragma unroll
    for (int a = 0; a < 4; a++) bs[a] = bias[o0 + a];
    if (sec < 2) {
      __bf16* dst = (sec == 0 ? qT : kT) + headbase * (size_t)(HW * HD);
#pragma unroll
      for (int c2 = 0; c2 < 4; c2++) {
        int j = j0g + c2;
        bf16x4 pk;
#pragma unroll
        for (int a = 0; a < 4; a++) pk[a] = (__bf16)(acc[a][c2] + bs[a]);
        *(bf16x4*)(dst + (size_t)j * HD + d0) = pk;
      }
    } else {
      __bf16* dst = vN + headbase * (size_t)(HD * HW);
#pragma unroll
      for (int a = 0; a < 4; a++) {
        bf16x4 pk;
#pragma unroll
        for (int c2 = 0; c2 < 4; c2++) pk[c2] = (__bf16)(acc[a][c2] + bs[a]);
        *(bf16x4*)(dst + (size_t)(d0 + a) * HW + j0g) = pk;
      }
    }
  }
}

// ---------------- MFMA flash attention ----------------
// qT,kT: [64 heads][1024][64] bf16 ; vN: [64 heads][64][1024] bf16
// out: fp32 [8][512][1024]. Block: 4 waves, 128 query rows (32/wave).
__global__ __launch_bounds__(256) void attn_mfma_kernel(const __bf16* __restrict__ qT,
                                                        const __bf16* __restrict__ kT,
                                                        const __bf16* __restrict__ vN,
                                                        float* __restrict__ attn) {
  int qt = blockIdx.x;   // 0..7
  int bh = blockIdx.y;   // 0..63
  int tid = threadIdx.x;
  int wid = tid >> 6;
  int lane = tid & 63;
  int l15 = lane & 15;
  int lhi = lane >> 4;   // 0..3

  const __bf16* qh = qT + (size_t)bh * HW * HD;
  const __bf16* kh = kT + (size_t)bh * HW * HD;
  const __bf16* vh = vN + (size_t)bh * HD * HW;

  __shared__ __align__(16) char smem[32768];
  char* kt = smem;                       // 8 KB: K^T tile [64 j][64 d], XOR-swz
  char* vt = smem + 8192;                // 8 KB: V tile  [64 d][64 j], XOR-swz
  char* pb = smem + 16384 + wid * 4096;  // 4 KB/wave: P [32 i][64 j], XOR-swz

  int i0 = qt * 128 + wid * 32;

  // Q fragments: A[row=l15][k=lhi*8+e], k-step ks covers d = ks*32..+31
  bf16x8 qf[2][2];
#pragma unroll
  for (int it = 0; it < 2; it++)
#pragma unroll
    for (int ks = 0; ks < 2; ks++) {
      int row = i0 + it * 16 + l15;
      qf[it][ks] = *(const bf16x8*)(qh + (size_t)row * HD + ks * 32 + lhi * 8);
    }

  f32x4 accO[2][4] = {};
  float m[2][4], l[2][4];
#pragma unroll
  for (int it = 0; it < 2; it++)
#pragma unroll
    for (int r = 0; r < 4; r++) { m[it][r] = -1e30f; l[it][r] = 0.f; }

  for (int t = 0; t < 16; ++t) {
    int j0 = t * 64;
    __syncthreads();
    // stage K^T and V tiles: 512 chunks of 16B each, 2 per thread
#pragma unroll
    for (int s = 0; s < 2; ++s) {
      int L = tid + s * 256;
      int r = L >> 3, c = L & 7;
      uint4 kd = *(const uint4*)((const char*)kh + (size_t)(j0 + r) * 128 + c * 16);
      uint4 vd = *(const uint4*)((const char*)vh + (size_t)r * 2048 + j0 * 2 + c * 16);
      *(uint4*)(kt + r * 128 + ((c ^ (r & 7)) << 4)) = kd;
      *(uint4*)(vt + r * 128 + ((c ^ (r & 7)) << 4)) = vd;
    }
    __syncthreads();

    // ---- QK^T: S[32 i][64 j] per wave ----
    f32x4 s_[2][4] = {};
#pragma unroll
    for (int ks = 0; ks < 2; ++ks)
#pragma unroll
      for (int jt = 0; jt < 4; ++jt) {
        int j = jt * 16 + l15;
        int c = ks * 4 + lhi;
        bf16x8 bk = *(const bf16x8*)(kt + j * 128 + ((c ^ (j & 7)) << 4));
        s_[0][jt] = __builtin_amdgcn_mfma_f32_16x16x32_bf16(qf[0][ks], bk, s_[0][jt], 0, 0, 0);
        s_[1][jt] = __builtin_amdgcn_mfma_f32_16x16x32_bf16(qf[1][ks], bk, s_[1][jt], 0, 0, 0);
      }

    // ---- online softmax (rows lane-group-local) ----
#pragma unroll
    for (int it = 0; it < 2; ++it) {
      float pm[4];
#pragma unroll
      for (int r = 0; r < 4; r++) {
        pm[r] = -1e30f;
#pragma unroll
        for (int jt = 0; jt < 4; ++jt) {
          s_[it][jt][r] *= 0.125f;
          pm[r] = fmaxf(pm[r], s_[it][jt][r]);
        }
      }
#pragma unroll
      for (int off = 1; off < 16; off <<= 1)
#pragma unroll
        for (int r = 0; r < 4; r++) pm[r] = fmaxf(pm[r], __shfl_xor(pm[r], off));
      float corr[4];
#pragma unroll
      for (int r = 0; r < 4; r++) {
        float nm = fmaxf(m[it][r], pm[r]);
        corr[r] = __expf(m[it][r] - nm);
        m[it][r] = nm;
      }
      float rsum[4] = {0.f, 0.f, 0.f, 0.f};
#pragma unroll
      for (int jt = 0; jt < 4; ++jt)
#pragma unroll
        for (int r = 0; r < 4; r++) {
          float p = __expf(s_[it][jt][r] - m[it][r]);
          s_[it][jt][r] = p;
          rsum[r] += p;
        }
#pragma unroll
      for (int off = 1; off < 16; off <<= 1)
#pragma unroll
        for (int r = 0; r < 4; r++) rsum[r] += __shfl_xor(rsum[r], off);
#pragma unroll
      for (int r = 0; r < 4; r++) l[it][r] = l[it][r] * corr[r] + rsum[r];
#pragma unroll
      for (int dt = 0; dt < 4; ++dt)
#pragma unroll
        for (int r = 0; r < 4; r++) accO[it][dt][r] *= corr[r];
      // write P tile (bf16, XOR-swizzled, per-wave buffer)
#pragma unroll
      for (int jt = 0; jt < 4; ++jt)
#pragma unroll
        for (int r = 0; r < 4; r++) {
          int row = it * 16 + lhi * 4 + r;
          int j = jt * 16 + l15;
          int off2 = row * 128 + (((j >> 3) ^ (row & 7)) << 4) + (j & 7) * 2;
          *(__bf16*)(pb + off2) = (__bf16)s_[it][jt][r];
        }
    }

    // ---- PV: O += P[32 i][64 j] * V^T[64 j][64 d] ----
#pragma unroll
    for (int kj = 0; kj < 2; ++kj) {
      bf16x8 pa[2];
#pragma unroll
      for (int it = 0; it < 2; ++it) {
        int row = it * 16 + l15;
        int c = kj * 4 + lhi;
        pa[it] = *(const bf16x8*)(pb + row * 128 + ((c ^ (row & 7)) << 4));
      }
#pragma unroll
      for (int dt = 0; dt < 4; ++dt) {
        int d = dt * 16 + l15;
        int c = kj * 4 + lhi;
        bf16x8 bv = *(const bf16x8*)(vt + d * 128 + ((c ^ (d & 7)) << 4));
        accO[0][dt] = __builtin_amdgcn_mfma_f32_16x16x32_bf16(pa[0], bv, accO[0][dt], 0, 0, 0);
        accO[1][dt] = __builtin_amdgcn_mfma_f32_16x16x32_bf16(pa[1], bv, accO[1][dt], 0, 0, 0);
      }
    }
  }

  // epilogue: out[b][c=h*64+d][i] fp32
  int b = bh >> 3, hh = bh & 7;
  float* op = attn + ((size_t)b * C + hh * 64) * HW;
#pragma unroll
  for (int it = 0; it < 2; ++it)
#pragma unroll
    for (int r = 0; r < 4; r++) {
      float inv = 1.f / l[it][r];
      int i = i0 + it * 16 + lhi * 4 + r;
#pragma unroll
      for (int dt = 0; dt < 4; ++dt)
        op[(size_t)(dt * 16 + l15) * HW + i] = accO[it][dt][r] * inv;
    }
}

extern "C" void kernel_launch(void* const* d_in, const int* in_sizes, int n_in,
                              void* d_out, int out_size, void* d_ws, size_t ws_size,
                              hipStream_t stream) {
  const float* x = (const float*)d_in[0];
  const float* gamma = (const float*)d_in[1];
  const float* beta = (const float*)d_in[2];
  const float* w_qkv = (const float*)d_in[3];
  const float* b_qkv = (const float*)d_in[4];
  const float* w_out = (const float*)d_in[5];
  const float* b_out = (const float*)d_in[6];
  float* out = (float*)d_out;

  char* ws = (char*)d_ws;
  float* xn = (float*)ws;                               // 16 MB fp32 (reused as attn out)
  __bf16* qT = (__bf16*)(ws + (size_t)16 * 1024 * 1024);  // 8 MB
  __bf16* kT = (__bf16*)(ws + (size_t)24 * 1024 * 1024);  // 8 MB
  __bf16* vN = (__bf16*)(ws + (size_t)32 * 1024 * 1024);  // 8 MB

  // 1. GroupNorm
  gn_kernel<<<dim3(256), 256, 0, stream>>>(x, gamma, beta, xn);
  // 2. QKV projection -> bf16 transposed layouts
  conv1x1_kernel<1><<<dim3(16, 24, 8), 256, 0, stream>>>(w_qkv, b_qkv, xn, nullptr, nullptr,
                                                         qT, kT, vN, 3 * C);
  // 3. MFMA flash attention (overwrites xn with [b][c][hw] fp32 output)
  attn_mfma_kernel<<<dim3(8, 64), 256, 0, stream>>>(qT, kT, vN, xn);
  // 4. Output projection + bias + residual
  conv1x1_kernel<0><<<dim3(16, 8, 8), 256, 0, stream>>>(w_out, b_out, xn, x, out, nullptr,
                                                        nullptr, nullptr, C);
}

// Round 4
// 193.521 us; speedup vs baseline: 5.0299x; 2.1450x over previous
//
#include <hip/hip_runtime.h>
#include <math.h>

#define NHEADS 8
#define C 512
#define HW 1024
#define HD 64

typedef __bf16 bf16x8 __attribute__((ext_vector_type(8)));
typedef __bf16 bf16x4 __attribute__((ext_vector_type(4)));
typedef float f32x4 __attribute__((ext_vector_type(4)));

// ---------------- weight fp32 -> bf16 convert (both W's in one launch) ------
__global__ __launch_bounds__(256) void wcvt_kernel(const float* __restrict__ w1,
                                                   __bf16* __restrict__ o1,
                                                   const float* __restrict__ w2,
                                                   __bf16* __restrict__ o2) {
  int id = blockIdx.x * 2048 + threadIdx.x * 8;
  const float* src;
  __bf16* dst;
  int off;
  if (id < 786432) { src = w1; dst = o1; off = id; }
  else { src = w2; dst = o2; off = id - 786432; }
  float4 a = *(const float4*)(src + off);
  float4 b = *(const float4*)(src + off + 4);
  bf16x8 o;
  o[0] = (__bf16)a.x; o[1] = (__bf16)a.y; o[2] = (__bf16)a.z; o[3] = (__bf16)a.w;
  o[4] = (__bf16)b.x; o[5] = (__bf16)b.y; o[6] = (__bf16)b.z; o[7] = (__bf16)b.w;
  *(bf16x8*)(dst + off) = o;
}

// ---------------- GroupNorm -> xnT [b][j=hw][c] bf16 ----------------
__global__ __launch_bounds__(256) void gn_kernel(const float* __restrict__ x,
                                                 const float* __restrict__ gamma,
                                                 const float* __restrict__ beta,
                                                 __bf16* __restrict__ xnT) {
  int b = blockIdx.x >> 5, g = blockIdx.x & 31;
  const size_t base = ((size_t)b * C + (size_t)g * 16) * HW;
  const float4* xp = (const float4*)(x + base);
  int tid = threadIdx.x;

  float s = 0.f, ss = 0.f;
  float4 v[16];
#pragma unroll
  for (int it = 0; it < 16; it++) {
    v[it] = xp[tid + it * 256];
    s += v[it].x + v[it].y + v[it].z + v[it].w;
    ss += v[it].x * v[it].x + v[it].y * v[it].y + v[it].z * v[it].z + v[it].w * v[it].w;
  }
#pragma unroll
  for (int off = 32; off > 0; off >>= 1) {
    s += __shfl_down(s, off);
    ss += __shfl_down(ss, off);
  }
  __shared__ float red[8];
  __shared__ float mi[2];
  int wid = tid >> 6;
  if ((tid & 63) == 0) { red[wid] = s; red[4 + wid] = ss; }
  __syncthreads();
  if (tid == 0) {
    float S = red[0] + red[1] + red[2] + red[3];
    float SS = red[4] + red[5] + red[6] + red[7];
    float mean = S * (1.f / 16384.f);
    float var = SS * (1.f / 16384.f) - mean * mean;
    mi[0] = mean;
    mi[1] = rsqrtf(var + 1e-5f);
  }
  __syncthreads();
  float mean = mi[0], inv = mi[1];
  float ga[16], be[16];
#pragma unroll
  for (int it = 0; it < 16; it++) {
    float g_ = gamma[g * 16 + it] * inv;
    ga[it] = g_;
    be[it] = beta[g * 16 + it] - mean * g_;
  }
  // thread owns j = tid*4..+3 for channels g*16..g*16+15 -> write xnT[j][g*16..+15]
  __bf16* dstb = xnT + ((size_t)b * HW + (size_t)tid * 4) * C + g * 16;
#pragma unroll
  for (int jj = 0; jj < 4; jj++) {
    bf16x8 w0, w1;
#pragma unroll
    for (int e = 0; e < 8; e++) {
      w0[e] = (__bf16)(((const float*)&v[e])[jj] * ga[e] + be[e]);
      w1[e] = (__bf16)(((const float*)&v[e + 8])[jj] * ga[e + 8] + be[e + 8]);
    }
    *(bf16x8*)(dstb + (size_t)jj * C) = w0;
    *(bf16x8*)(dstb + (size_t)jj * C + 8) = w1;
  }
}

// ---------------- MFMA GEMM: D = R @ C^T, both [rows][512] bf16 row-major ---
// 128x128 tile, BK=64, 4 waves (2x2), per-wave 64x64 = 4x4 16x16 frags.
// EPI 0: D[j][o] -> qT/kT[bh][i][d] bf16 (+bias)
// EPI 1: D[d'][j] -> vN[bh][d][j] bf16 (+bias, bias pre-offset)
// EPI 2: D[o][j] -> Yout fp32 = D + bias + resid
template <int EPI>
__global__ __launch_bounds__(256) void gemm_rr(const __bf16* __restrict__ Rp, size_t Rbs,
                                               const __bf16* __restrict__ Cp, size_t Cbs,
                                               const float* __restrict__ bias,
                                               __bf16* __restrict__ q_or_v,
                                               __bf16* __restrict__ kT,
                                               const float* __restrict__ resid,
                                               float* __restrict__ Yout) {
  int bx = blockIdx.x, by = blockIdx.y, b = blockIdx.z;
  int tid = threadIdx.x, wid = tid >> 6, lane = tid & 63;
  int l15 = lane & 15, lhi = lane >> 4;
  int wr = wid >> 1, wc = wid & 1;

  const __bf16* Rb = Rp + (size_t)b * Rbs + (size_t)by * 128 * 512;
  const __bf16* Cb = Cp + (size_t)b * Cbs + (size_t)bx * 128 * 512;

  __shared__ __align__(16) char smem[32768];
  char* Rs = smem;           // [128 rows][64 k] bf16, XOR-swizzled 16B chunks
  char* Cs = smem + 16384;

  f32x4 acc[4][4] = {};
  int srow = tid >> 1, sc0 = (tid & 1) * 4;

  for (int kk = 0; kk < 512; kk += 64) {
    __syncthreads();
    const __bf16* rg = Rb + (size_t)srow * 512 + kk + sc0 * 8;
    const __bf16* cg = Cb + (size_t)srow * 512 + kk + sc0 * 8;
#pragma unroll
    for (int q = 0; q < 4; q++) {
      int c = sc0 + q;
      int o = srow * 128 + ((c ^ (srow & 7)) << 4);
      *(uint4*)(Rs + o) = *(const uint4*)(rg + q * 8);
      *(uint4*)(Cs + o) = *(const uint4*)(cg + q * 8);
    }
    __syncthreads();
#pragma unroll
    for (int ks = 0; ks < 2; ks++) {
      bf16x8 ar[4], br[4];
      int c = ks * 4 + lhi;
#pragma unroll
      for (int m = 0; m < 4; m++) {
        int row = wr * 64 + m * 16 + l15;
        ar[m] = *(const bf16x8*)(Rs + row * 128 + ((c ^ (row & 7)) << 4));
      }
#pragma unroll
      for (int n = 0; n < 4; n++) {
        int row = wc * 64 + n * 16 + l15;
        br[n] = *(const bf16x8*)(Cs + row * 128 + ((c ^ (row & 7)) << 4));
      }
#pragma unroll
      for (int m = 0; m < 4; m++)
#pragma unroll
        for (int n = 0; n < 4; n++)
          acc[m][n] = __builtin_amdgcn_mfma_f32_16x16x32_bf16(ar[m], br[n], acc[m][n], 0, 0, 0);
    }
  }

  int rbase = by * 128 + wr * 64;
  int cbase = bx * 128 + wc * 64;

  if (EPI == 0) {
#pragma unroll
    for (int n = 0; n < 4; n++) {
      int col = cbase + n * 16 + l15;  // o in 0..1023
      int sec = col >> 9;
      int h = (col >> 6) & 7;
      int d = col & 63;
      __bf16* dst0 = (sec ? kT : q_or_v) + ((size_t)b * 8 + h) * (size_t)(HW * HD) + d;
      float bs = bias[col];
#pragma unroll
      for (int m = 0; m < 4; m++)
#pragma unroll
        for (int r = 0; r < 4; r++) {
          int i = rbase + m * 16 + lhi * 4 + r;
          dst0[(size_t)i * HD] = (__bf16)(acc[m][n][r] + bs);
        }
    }
  } else if (EPI == 1) {
#pragma unroll
    for (int m = 0; m < 4; m++)
#pragma unroll
      for (int r = 0; r < 4; r++) {
        int row = rbase + m * 16 + lhi * 4 + r;  // 0..511 = h*64+d
        int h = row >> 6, d = row & 63;
        float bs = bias[row];
        __bf16* dst = q_or_v + (((size_t)b * 8 + h) * HD + d) * HW;
#pragma unroll
        for (int n = 0; n < 4; n++) {
          int j = cbase + n * 16 + l15;
          dst[j] = (__bf16)(acc[m][n][r] + bs);
        }
      }
  } else {
#pragma unroll
    for (int m = 0; m < 4; m++)
#pragma unroll
      for (int r = 0; r < 4; r++) {
        int o = rbase + m * 16 + lhi * 4 + r;
        float bs = bias[o];
        size_t base2 = ((size_t)b * C + o) * HW;
#pragma unroll
        for (int n = 0; n < 4; n++) {
          int j = cbase + n * 16 + l15;
          Yout[base2 + j] = acc[m][n][r] + bs + resid[base2 + j];
        }
      }
  }
}

// ---------------- MFMA flash attention ----------------
// qT,kT: [64 heads][1024][64] bf16 ; vN: [64 heads][64][1024] bf16
// out: aT [b][j][c] bf16 (for the out-projection GEMM).
__global__ __launch_bounds__(256) void attn_mfma_kernel(const __bf16* __restrict__ qT,
                                                        const __bf16* __restrict__ kT,
                                                        const __bf16* __restrict__ vN,
                                                        __bf16* __restrict__ aT) {
  int qt = blockIdx.x;   // 0..7
  int bh = blockIdx.y;   // 0..63
  int tid = threadIdx.x;
  int wid = tid >> 6;
  int lane = tid & 63;
  int l15 = lane & 15;
  int lhi = lane >> 4;

  const __bf16* qh = qT + (size_t)bh * HW * HD;
  const __bf16* kh = kT + (size_t)bh * HW * HD;
  const __bf16* vh = vN + (size_t)bh * HD * HW;

  __shared__ __align__(16) char smem[32768];
  char* kt = smem;                       // 8 KB: K^T tile [64 j][64 d], XOR-swz
  char* vt = smem + 8192;                // 8 KB: V tile  [64 d][64 j], XOR-swz
  char* pb = smem + 16384 + wid * 4096;  // 4 KB/wave: P [32 i][64 j], XOR-swz

  int i0 = qt * 128 + wid * 32;

  bf16x8 qf[2][2];
#pragma unroll
  for (int it = 0; it < 2; it++)
#pragma unroll
    for (int ks = 0; ks < 2; ks++) {
      int row = i0 + it * 16 + l15;
      qf[it][ks] = *(const bf16x8*)(qh + (size_t)row * HD + ks * 32 + lhi * 8);
    }

  f32x4 accO[2][4] = {};
  float m[2][4], l[2][4];
#pragma unroll
  for (int it = 0; it < 2; it++)
#pragma unroll
    for (int r = 0; r < 4; r++) { m[it][r] = -1e30f; l[it][r] = 0.f; }

  for (int t = 0; t < 16; ++t) {
    int j0 = t * 64;
    __syncthreads();
#pragma unroll
    for (int s = 0; s < 2; ++s) {
      int L = tid + s * 256;
      int r = L >> 3, c = L & 7;
      uint4 kd = *(const uint4*)((const char*)kh + (size_t)(j0 + r) * 128 + c * 16);
      uint4 vd = *(const uint4*)((const char*)vh + (size_t)r * 2048 + j0 * 2 + c * 16);
      *(uint4*)(kt + r * 128 + ((c ^ (r & 7)) << 4)) = kd;
      *(uint4*)(vt + r * 128 + ((c ^ (r & 7)) << 4)) = vd;
    }
    __syncthreads();

    f32x4 s_[2][4] = {};
#pragma unroll
    for (int ks = 0; ks < 2; ++ks)
#pragma unroll
      for (int jt = 0; jt < 4; ++jt) {
        int j = jt * 16 + l15;
        int c = ks * 4 + lhi;
        bf16x8 bk = *(const bf16x8*)(kt + j * 128 + ((c ^ (j & 7)) << 4));
        s_[0][jt] = __builtin_amdgcn_mfma_f32_16x16x32_bf16(qf[0][ks], bk, s_[0][jt], 0, 0, 0);
        s_[1][jt] = __builtin_amdgcn_mfma_f32_16x16x32_bf16(qf[1][ks], bk, s_[1][jt], 0, 0, 0);
      }

#pragma unroll
    for (int it = 0; it < 2; ++it) {
      float pm[4];
#pragma unroll
      for (int r = 0; r < 4; r++) {
        pm[r] = -1e30f;
#pragma unroll
        for (int jt = 0; jt < 4; ++jt) {
          s_[it][jt][r] *= 0.125f;
          pm[r] = fmaxf(pm[r], s_[it][jt][r]);
        }
      }
#pragma unroll
      for (int off = 1; off < 16; off <<= 1)
#pragma unroll
        for (int r = 0; r < 4; r++) pm[r] = fmaxf(pm[r], __shfl_xor(pm[r], off));
      float corr[4];
#pragma unroll
      for (int r = 0; r < 4; r++) {
        float nm = fmaxf(m[it][r], pm[r]);
        corr[r] = __expf(m[it][r] - nm);
        m[it][r] = nm;
      }
      float rsum[4] = {0.f, 0.f, 0.f, 0.f};
#pragma unroll
      for (int jt = 0; jt < 4; ++jt)
#pragma unroll
        for (int r = 0; r < 4; r++) {
          float p = __expf(s_[it][jt][r] - m[it][r]);
          s_[it][jt][r] = p;
          rsum[r] += p;
        }
#pragma unroll
      for (int off = 1; off < 16; off <<= 1)
#pragma unroll
        for (int r = 0; r < 4; r++) rsum[r] += __shfl_xor(rsum[r], off);
#pragma unroll
      for (int r = 0; r < 4; r++) l[it][r] = l[it][r] * corr[r] + rsum[r];
#pragma unroll
      for (int dt = 0; dt < 4; ++dt)
#pragma unroll
        for (int r = 0; r < 4; r++) accO[it][dt][r] *= corr[r];
#pragma unroll
      for (int jt = 0; jt < 4; ++jt)
#pragma unroll
        for (int r = 0; r < 4; r++) {
          int row = it * 16 + lhi * 4 + r;
          int j = jt * 16 + l15;
          int off2 = row * 128 + (((j >> 3) ^ (row & 7)) << 4) + (j & 7) * 2;
          *(__bf16*)(pb + off2) = (__bf16)s_[it][jt][r];
        }
    }

#pragma unroll
    for (int kj = 0; kj < 2; ++kj) {
      bf16x8 pa[2];
#pragma unroll
      for (int it = 0; it < 2; ++it) {
        int row = it * 16 + l15;
        int c = kj * 4 + lhi;
        pa[it] = *(const bf16x8*)(pb + row * 128 + ((c ^ (row & 7)) << 4));
      }
#pragma unroll
      for (int dt = 0; dt < 4; ++dt) {
        int d = dt * 16 + l15;
        int c = kj * 4 + lhi;
        bf16x8 bv = *(const bf16x8*)(vt + d * 128 + ((c ^ (d & 7)) << 4));
        accO[0][dt] = __builtin_amdgcn_mfma_f32_16x16x32_bf16(pa[0], bv, accO[0][dt], 0, 0, 0);
        accO[1][dt] = __builtin_amdgcn_mfma_f32_16x16x32_bf16(pa[1], bv, accO[1][dt], 0, 0, 0);
      }
    }
  }

  // epilogue: per-wave LDS transpose -> aT[b][i][h*64+d] bf16 coalesced
  __syncthreads();
  __bf16* Lo = (__bf16*)(smem + wid * 4608);  // [32][72] bf16
#pragma unroll
  for (int it = 0; it < 2; ++it)
#pragma unroll
    for (int r = 0; r < 4; r++) {
      float inv = 1.f / l[it][r];
      int iloc = it * 16 + lhi * 4 + r;
#pragma unroll
      for (int dt = 0; dt < 4; ++dt)
        Lo[iloc * 72 + dt * 16 + l15] = (__bf16)(accO[it][dt][r] * inv);
    }
  __syncthreads();
  int b = bh >> 3, hh = bh & 7;
  int iloc = lane >> 1, dh = (lane & 1) * 32;
  __bf16* dst = aT + ((size_t)b * HW + i0 + iloc) * C + hh * 64 + dh;
  const __bf16* srcl = Lo + iloc * 72 + dh;
#pragma unroll
  for (int s2 = 0; s2 < 4; s2++)
    *(uint4*)(dst + s2 * 8) = *(const uint4*)(srcl + s2 * 8);
}

extern "C" void kernel_launch(void* const* d_in, const int* in_sizes, int n_in,
                              void* d_out, int out_size, void* d_ws, size_t ws_size,
                              hipStream_t stream) {
  const float* x = (const float*)d_in[0];
  const float* gamma = (const float*)d_in[1];
  const float* beta = (const float*)d_in[2];
  const float* w_qkv = (const float*)d_in[3];
  const float* b_qkv = (const float*)d_in[4];
  const float* w_out = (const float*)d_in[5];
  const float* b_out = (const float*)d_in[6];
  float* out = (float*)d_out;

  char* ws = (char*)d_ws;
  const size_t MB = 1024 * 1024;
  __bf16* xnT = (__bf16*)ws;                  // 8 MB [8][1024][512]
  __bf16* qT  = (__bf16*)(ws + 8 * MB);       // 8 MB [64][1024][64]
  __bf16* kT  = (__bf16*)(ws + 16 * MB);      // 8 MB
  __bf16* vN  = (__bf16*)(ws + 24 * MB);      // 8 MB [64][64][1024]
  __bf16* aT  = (__bf16*)(ws + 32 * MB);      // 8 MB [8][1024][512]
  __bf16* wbq = (__bf16*)(ws + 40 * MB);      // 1.5 MB [1536][512]
  __bf16* wbo = (__bf16*)(ws + 42 * MB);      // 0.5 MB [512][512]

  // 1. weights -> bf16
  wcvt_kernel<<<dim3(512), 256, 0, stream>>>(w_qkv, wbq, w_out, wbo);
  // 2. GroupNorm -> xnT bf16 [b][j][c]
  gn_kernel<<<dim3(256), 256, 0, stream>>>(x, gamma, beta, xnT);
  // 3. Q,K projection: D[j][o] = xnT @ Wqk^T
  gemm_rr<0><<<dim3(8, 8, 8), 256, 0, stream>>>(xnT, (size_t)HW * C, wbq, 0,
                                                b_qkv, qT, kT, nullptr, nullptr);
  // 4. V projection: D[d'][j] = Wv @ xnT^T
  gemm_rr<1><<<dim3(8, 4, 8), 256, 0, stream>>>(wbq + (size_t)1024 * 512, 0, xnT, (size_t)HW * C,
                                                b_qkv + 1024, vN, nullptr, nullptr, nullptr);
  // 5. MFMA flash attention -> aT bf16 [b][j][c]
  attn_mfma_kernel<<<dim3(8, 64), 256, 0, stream>>>(qT, kT, vN, aT);
  // 6. Output projection: D[o][j] = Wout @ aT^T + bias + residual
  gemm_rr<2><<<dim3(8, 4, 8), 256, 0, stream>>>(wbo, 0, aT, (size_t)HW * C,
                                                b_out, nullptr, nullptr, x, out);
}

// Round 9
// 173.245 us; speedup vs baseline: 5.6185x; 1.1170x over previous
//
#include <hip/hip_runtime.h>
#include <math.h>

#define NHEADS 8
#define C 512
#define HW 1024
#define HD 64

typedef __bf16 bf16x8 __attribute__((ext_vector_type(8)));
typedef __bf16 bf16x4 __attribute__((ext_vector_type(4)));
typedef float f32x4 __attribute__((ext_vector_type(4)));

// ---------------- weight fp32 -> bf16 convert (both W's in one launch) ------
__global__ __launch_bounds__(256) void wcvt_kernel(const float* __restrict__ w1,
                                                   __bf16* __restrict__ o1,
                                                   const float* __restrict__ w2,
                                                   __bf16* __restrict__ o2) {
  int id = blockIdx.x * 2048 + threadIdx.x * 8;
  const float* src;
  __bf16* dst;
  int off;
  if (id < 786432) { src = w1; dst = o1; off = id; }
  else { src = w2; dst = o2; off = id - 786432; }
  float4 a = *(const float4*)(src + off);
  float4 b = *(const float4*)(src + off + 4);
  bf16x8 o;
  o[0] = (__bf16)a.x; o[1] = (__bf16)a.y; o[2] = (__bf16)a.z; o[3] = (__bf16)a.w;
  o[4] = (__bf16)b.x; o[5] = (__bf16)b.y; o[6] = (__bf16)b.z; o[7] = (__bf16)b.w;
  *(bf16x8*)(dst + off) = o;
}

// ---------------- GroupNorm -> xnT [b][j=hw][c] bf16 ----------------
__global__ __launch_bounds__(256) void gn_kernel(const float* __restrict__ x,
                                                 const float* __restrict__ gamma,
                                                 const float* __restrict__ beta,
                                                 __bf16* __restrict__ xnT) {
  int b = blockIdx.x >> 5, g = blockIdx.x & 31;
  const size_t base = ((size_t)b * C + (size_t)g * 16) * HW;
  const float4* xp = (const float4*)(x + base);
  int tid = threadIdx.x;

  float s = 0.f, ss = 0.f;
  float4 v[16];
#pragma unroll
  for (int it = 0; it < 16; it++) {
    v[it] = xp[tid + it * 256];
    s += v[it].x + v[it].y + v[it].z + v[it].w;
    ss += v[it].x * v[it].x + v[it].y * v[it].y + v[it].z * v[it].z + v[it].w * v[it].w;
  }
#pragma unroll
  for (int off = 32; off > 0; off >>= 1) {
    s += __shfl_down(s, off);
    ss += __shfl_down(ss, off);
  }
  __shared__ float red[8];
  __shared__ float mi[2];
  int wid = tid >> 6;
  if ((tid & 63) == 0) { red[wid] = s; red[4 + wid] = ss; }
  __syncthreads();
  if (tid == 0) {
    float S = red[0] + red[1] + red[2] + red[3];
    float SS = red[4] + red[5] + red[6] + red[7];
    float mean = S * (1.f / 16384.f);
    float var = SS * (1.f / 16384.f) - mean * mean;
    mi[0] = mean;
    mi[1] = rsqrtf(var + 1e-5f);
  }
  __syncthreads();
  float mean = mi[0], inv = mi[1];
  float ga[16], be[16];
#pragma unroll
  for (int it = 0; it < 16; it++) {
    float g_ = gamma[g * 16 + it] * inv;
    ga[it] = g_;
    be[it] = beta[g * 16 + it] - mean * g_;
  }
  __bf16* dstb = xnT + ((size_t)b * HW + (size_t)tid * 4) * C + g * 16;
#pragma unroll
  for (int jj = 0; jj < 4; jj++) {
    bf16x8 w0, w1;
#pragma unroll
    for (int e = 0; e < 8; e++) {
      w0[e] = (__bf16)(((const float*)&v[e])[jj] * ga[e] + be[e]);
      w1[e] = (__bf16)(((const float*)&v[e + 8])[jj] * ga[e + 8] + be[e + 8]);
    }
    *(bf16x8*)(dstb + (size_t)jj * C) = w0;
    *(bf16x8*)(dstb + (size_t)jj * C + 8) = w1;
  }
}

// ---------------- MFMA GEMM: D = R @ C^T, both [rows][512] bf16 row-major ---
template <int EPI>
__global__ __launch_bounds__(256) void gemm_rr(const __bf16* __restrict__ Rp, size_t Rbs,
                                               const __bf16* __restrict__ Cp, size_t Cbs,
                                               const float* __restrict__ bias,
                                               __bf16* __restrict__ q_or_v,
                                               __bf16* __restrict__ kT,
                                               const float* __restrict__ resid,
                                               float* __restrict__ Yout) {
  int bx = blockIdx.x, by = blockIdx.y, b = blockIdx.z;
  int tid = threadIdx.x, wid = tid >> 6, lane = tid & 63;
  int l15 = lane & 15, lhi = lane >> 4;
  int wr = wid >> 1, wc = wid & 1;

  const __bf16* Rb = Rp + (size_t)b * Rbs + (size_t)by * 128 * 512;
  const __bf16* Cb = Cp + (size_t)b * Cbs + (size_t)bx * 128 * 512;

  __shared__ __align__(16) char smem[32768];
  char* Rs = smem;
  char* Cs = smem + 16384;

  f32x4 acc[4][4] = {};
  int srow = tid >> 1, sc0 = (tid & 1) * 4;

  for (int kk = 0; kk < 512; kk += 64) {
    __syncthreads();
    const __bf16* rg = Rb + (size_t)srow * 512 + kk + sc0 * 8;
    const __bf16* cg = Cb + (size_t)srow * 512 + kk + sc0 * 8;
#pragma unroll
    for (int q = 0; q < 4; q++) {
      int c = sc0 + q;
      int o = srow * 128 + ((c ^ (srow & 7)) << 4);
      *(uint4*)(Rs + o) = *(const uint4*)(rg + q * 8);
      *(uint4*)(Cs + o) = *(const uint4*)(cg + q * 8);
    }
    __syncthreads();
#pragma unroll
    for (int ks = 0; ks < 2; ks++) {
      bf16x8 ar[4], br[4];
      int c = ks * 4 + lhi;
#pragma unroll
      for (int m = 0; m < 4; m++) {
        int row = wr * 64 + m * 16 + l15;
        ar[m] = *(const bf16x8*)(Rs + row * 128 + ((c ^ (row & 7)) << 4));
      }
#pragma unroll
      for (int n = 0; n < 4; n++) {
        int row = wc * 64 + n * 16 + l15;
        br[n] = *(const bf16x8*)(Cs + row * 128 + ((c ^ (row & 7)) << 4));
      }
#pragma unroll
      for (int m = 0; m < 4; m++)
#pragma unroll
        for (int n = 0; n < 4; n++)
          acc[m][n] = __builtin_amdgcn_mfma_f32_16x16x32_bf16(ar[m], br[n], acc[m][n], 0, 0, 0);
    }
  }

  int rbase = by * 128 + wr * 64;
  int cbase = bx * 128 + wc * 64;

  if (EPI == 0) {
#pragma unroll
    for (int n = 0; n < 4; n++) {
      int col = cbase + n * 16 + l15;
      int sec = col >> 9;
      int h = (col >> 6) & 7;
      int d = col & 63;
      __bf16* dst0 = (sec ? kT : q_or_v) + ((size_t)b * 8 + h) * (size_t)(HW * HD) + d;
      float bs = bias[col];
#pragma unroll
      for (int m = 0; m < 4; m++)
#pragma unroll
        for (int r = 0; r < 4; r++) {
          int i = rbase + m * 16 + lhi * 4 + r;
          dst0[(size_t)i * HD] = (__bf16)(acc[m][n][r] + bs);
        }
    }
  } else if (EPI == 1) {
#pragma unroll
    for (int m = 0; m < 4; m++)
#pragma unroll
      for (int r = 0; r < 4; r++) {
        int row = rbase + m * 16 + lhi * 4 + r;
        int h = row >> 6, d = row & 63;
        float bs = bias[row];
        __bf16* dst = q_or_v + (((size_t)b * 8 + h) * HD + d) * HW;
#pragma unroll
        for (int n = 0; n < 4; n++) {
          int j = cbase + n * 16 + l15;
          dst[j] = (__bf16)(acc[m][n][r] + bs);
        }
      }
  } else {
#pragma unroll
    for (int m = 0; m < 4; m++)
#pragma unroll
      for (int r = 0; r < 4; r++) {
        int o = rbase + m * 16 + lhi * 4 + r;
        float bs = bias[o];
        size_t base2 = ((size_t)b * C + o) * HW;
#pragma unroll
        for (int n = 0; n < 4; n++) {
          int j = cbase + n * 16 + l15;
          Yout[base2 + j] = acc[m][n][r] + bs + resid[base2 + j];
        }
      }
  }
}

// ---------------- MFMA flash attention (prefetch dbuf + defer-max) ---------
// qT,kT: [64 heads][1024][64] bf16 ; vN: [64 heads][64][1024] bf16
// Grid: flat 512; bh = id&63 so all 8 q-tiles of a head share one XCD's L2.
__global__ __launch_bounds__(256) void attn_mfma_kernel(const __bf16* __restrict__ qT,
                                                        const __bf16* __restrict__ kT,
                                                        const __bf16* __restrict__ vN,
                                                        __bf16* __restrict__ aT) {
  int bh = blockIdx.x & 63;
  int qt = blockIdx.x >> 6;
  int tid = threadIdx.x;
  int wid = tid >> 6;
  int lane = tid & 63;
  int l15 = lane & 15;
  int lhi = lane >> 4;

  const __bf16* qh = qT + (size_t)bh * HW * HD;
  const char* kh = (const char*)(kT + (size_t)bh * HW * HD);
  const char* vh = (const char*)(vN + (size_t)bh * HD * HW);

  __shared__ __align__(16) char smem[49152];
  // layout: buf0 K at 0, buf0 V at 8192; buf1 K at 16384, buf1 V at 24576;
  // per-wave P at 32768 + wid*4096  (no pointer arrays: LDS addrspace
  // array initializers fail to compile on gfx950)
  char* pb = smem + 32768 + wid * 4096;

  int i0 = qt * 128 + wid * 32;

  // Q fragments, pre-scaled by 1/8 (exact in bf16)
  bf16x8 qf[2][2];
#pragma unroll
  for (int it = 0; it < 2; it++)
#pragma unroll
    for (int ks = 0; ks < 2; ks++) {
      int row = i0 + it * 16 + l15;
      bf16x8 qv = *(const bf16x8*)(qh + (size_t)row * HD + ks * 32 + lhi * 8);
#pragma unroll
      for (int e = 0; e < 8; e++) qv[e] = (__bf16)((float)qv[e] * 0.125f);
      qf[it][ks] = qv;
    }

  // staging geometry: 2 chunks/thread for K and V each
  int sr = tid >> 3, sc = tid & 7;
  int sr2 = sr + 32;
  int swz1 = sr * 128 + ((sc ^ (sr & 7)) << 4);
  int swz2 = sr2 * 128 + ((sc ^ (sr2 & 7)) << 4);

  uint4 kr0, kr1, vr0, vr1;
  {  // tile 0 load + store to buf0
    kr0 = *(const uint4*)(kh + (size_t)sr * 128 + sc * 16);
    kr1 = *(const uint4*)(kh + (size_t)sr2 * 128 + sc * 16);
    vr0 = *(const uint4*)(vh + (size_t)sr * 2048 + sc * 16);
    vr1 = *(const uint4*)(vh + (size_t)sr2 * 2048 + sc * 16);
    *(uint4*)(smem + swz1) = kr0;
    *(uint4*)(smem + swz2) = kr1;
    *(uint4*)(smem + 8192 + swz1) = vr0;
    *(uint4*)(smem + 8192 + swz2) = vr1;
  }

  f32x4 accO[2][4] = {};
  f32x4 lacc[2] = {};
  float m[2][4];
#pragma unroll
  for (int it = 0; it < 2; it++)
#pragma unroll
    for (int r = 0; r < 4; r++) m[it][r] = -1e30f;

  bf16x8 ones;
#pragma unroll
  for (int e = 0; e < 8; e++) ones[e] = (__bf16)1.0f;

  for (int t = 0; t < 16; ++t) {
    if (t < 15) {  // prefetch next tile into regs (latency hides under compute)
      int j0n = (t + 1) * 64;
      kr0 = *(const uint4*)(kh + (size_t)(j0n + sr) * 128 + sc * 16);
      kr1 = *(const uint4*)(kh + (size_t)(j0n + sr2) * 128 + sc * 16);
      vr0 = *(const uint4*)(vh + (size_t)sr * 2048 + j0n * 2 + sc * 16);
      vr1 = *(const uint4*)(vh + (size_t)sr2 * 2048 + j0n * 2 + sc * 16);
    }
    __syncthreads();
    const char* kt = smem + ((t & 1) << 14);
    const char* vt = kt + 8192;

    // ---- QK^T ----
    f32x4 s_[2][4] = {};
#pragma unroll
    for (int ks = 0; ks < 2; ++ks)
#pragma unroll
      for (int jt = 0; jt < 4; ++jt) {
        int j = jt * 16 + l15;
        int c = ks * 4 + lhi;
        bf16x8 bk = *(const bf16x8*)(kt + j * 128 + ((c ^ (j & 7)) << 4));
        s_[0][jt] = __builtin_amdgcn_mfma_f32_16x16x32_bf16(qf[0][ks], bk, s_[0][jt], 0, 0, 0);
        s_[1][jt] = __builtin_amdgcn_mfma_f32_16x16x32_bf16(qf[1][ks], bk, s_[1][jt], 0, 0, 0);
      }

    // ---- defer-max online softmax ----
    float lm[2][4];
    int ok = 1;
#pragma unroll
    for (int it = 0; it < 2; ++it)
#pragma unroll
      for (int r = 0; r < 4; r++) {
        lm[it][r] = fmaxf(fmaxf(s_[it][0][r], s_[it][1][r]),
                          fmaxf(s_[it][2][r], s_[it][3][r]));
        ok &= (lm[it][r] <= m[it][r] + 8.f);
      }
    if (!__all(ok)) {
#pragma unroll
      for (int it = 0; it < 2; ++it) {
        float pm[4];
#pragma unroll
        for (int r = 0; r < 4; r++) pm[r] = lm[it][r];
#pragma unroll
        for (int off = 1; off < 16; off <<= 1)
#pragma unroll
          for (int r = 0; r < 4; r++) pm[r] = fmaxf(pm[r], __shfl_xor(pm[r], off));
#pragma unroll
        for (int r = 0; r < 4; r++) {
          float nm = fmaxf(m[it][r], pm[r]);
          float corr = __expf(m[it][r] - nm);
          m[it][r] = nm;
          lacc[it][r] *= corr;
#pragma unroll
          for (int dt = 0; dt < 4; ++dt) accO[it][dt][r] *= corr;
        }
      }
    }
    // P = exp(s - m), store bf16 to per-wave LDS
#pragma unroll
    for (int it = 0; it < 2; ++it)
#pragma unroll
      for (int jt = 0; jt < 4; ++jt)
#pragma unroll
        for (int r = 0; r < 4; r++) {
          float p = __expf(s_[it][jt][r] - m[it][r]);
          int row = it * 16 + lhi * 4 + r;
          int j = jt * 16 + l15;
          int off2 = row * 128 + (((j >> 3) ^ (row & 7)) << 4) + (j & 7) * 2;
          *(__bf16*)(pb + off2) = (__bf16)p;
        }

    // ---- PV + rowsum-by-MFMA ----
#pragma unroll
    for (int kj = 0; kj < 2; ++kj) {
      bf16x8 pa[2];
#pragma unroll
      for (int it = 0; it < 2; ++it) {
        int row = it * 16 + l15;
        int c = kj * 4 + lhi;
        pa[it] = *(const bf16x8*)(pb + row * 128 + ((c ^ (row & 7)) << 4));
      }
      lacc[0] = __builtin_amdgcn_mfma_f32_16x16x32_bf16(pa[0], ones, lacc[0], 0, 0, 0);
      lacc[1] = __builtin_amdgcn_mfma_f32_16x16x32_bf16(pa[1], ones, lacc[1], 0, 0, 0);
#pragma unroll
      for (int dt = 0; dt < 4; ++dt) {
        int d = dt * 16 + l15;
        int c = kj * 4 + lhi;
        bf16x8 bv = *(const bf16x8*)(vt + d * 128 + ((c ^ (d & 7)) << 4));
        accO[0][dt] = __builtin_amdgcn_mfma_f32_16x16x32_bf16(pa[0], bv, accO[0][dt], 0, 0, 0);
        accO[1][dt] = __builtin_amdgcn_mfma_f32_16x16x32_bf16(pa[1], bv, accO[1][dt], 0, 0, 0);
      }
    }

    if (t < 15) {  // write prefetched regs into the other buffer
      char* ktn = smem + (((t + 1) & 1) << 14);
      *(uint4*)(ktn + swz1) = kr0;
      *(uint4*)(ktn + swz2) = kr1;
      *(uint4*)(ktn + 8192 + swz1) = vr0;
      *(uint4*)(ktn + 8192 + swz2) = vr1;
    }
  }

  // epilogue: per-wave LDS transpose -> aT[b][i][h*64+d] bf16 coalesced
  __syncthreads();
  __bf16* Lo = (__bf16*)(smem + wid * 4608);  // [32][72] bf16
#pragma unroll
  for (int it = 0; it < 2; ++it)
#pragma unroll
    for (int r = 0; r < 4; r++) {
      float inv = 1.f / lacc[it][r];
      int iloc = it * 16 + lhi * 4 + r;
#pragma unroll
      for (int dt = 0; dt < 4; ++dt)
        Lo[iloc * 72 + dt * 16 + l15] = (__bf16)(accO[it][dt][r] * inv);
    }
  __syncthreads();
  int b = bh >> 3, hh = bh & 7;
  int iloc = lane >> 1, dh = (lane & 1) * 32;
  __bf16* dst = aT + ((size_t)b * HW + i0 + iloc) * C + hh * 64 + dh;
  const __bf16* srcl = Lo + iloc * 72 + dh;
#pragma unroll
  for (int s2 = 0; s2 < 4; s2++)
    *(uint4*)(dst + s2 * 8) = *(const uint4*)(srcl + s2 * 8);
}

extern "C" void kernel_launch(void* const* d_in, const int* in_sizes, int n_in,
                              void* d_out, int out_size, void* d_ws, size_t ws_size,
                              hipStream_t stream) {
  const float* x = (const float*)d_in[0];
  const float* gamma = (const float*)d_in[1];
  const float* beta = (const float*)d_in[2];
  const float* w_qkv = (const float*)d_in[3];
  const float* b_qkv = (const float*)d_in[4];
  const float* w_out = (const float*)d_in[5];
  const float* b_out = (const float*)d_in[6];
  float* out = (float*)d_out;

  char* ws = (char*)d_ws;
  const size_t MB = 1024 * 1024;
  __bf16* xnT = (__bf16*)ws;                  // 8 MB [8][1024][512]
  __bf16* qT  = (__bf16*)(ws + 8 * MB);       // 8 MB [64][1024][64]
  __bf16* kT  = (__bf16*)(ws + 16 * MB);      // 8 MB
  __bf16* vN  = (__bf16*)(ws + 24 * MB);      // 8 MB [64][64][1024]
  __bf16* aT  = (__bf16*)(ws + 32 * MB);      // 8 MB [8][1024][512]
  __bf16* wbq = (__bf16*)(ws + 40 * MB);      // 1.5 MB [1536][512]
  __bf16* wbo = (__bf16*)(ws + 42 * MB);      // 0.5 MB [512][512]

  // 1. weights -> bf16
  wcvt_kernel<<<dim3(512), 256, 0, stream>>>(w_qkv, wbq, w_out, wbo);
  // 2. GroupNorm -> xnT bf16 [b][j][c]
  gn_kernel<<<dim3(256), 256, 0, stream>>>(x, gamma, beta, xnT);
  // 3. Q,K projection: D[j][o] = xnT @ Wqk^T
  gemm_rr<0><<<dim3(8, 8, 8), 256, 0, stream>>>(xnT, (size_t)HW * C, wbq, 0,
                                                b_qkv, qT, kT, nullptr, nullptr);
  // 4. V projection: D[d'][j] = Wv @ xnT^T
  gemm_rr<1><<<dim3(8, 4, 8), 256, 0, stream>>>(wbq + (size_t)1024 * 512, 0, xnT, (size_t)HW * C,
                                                b_qkv + 1024, vN, nullptr, nullptr, nullptr);
  // 5. MFMA flash attention -> aT bf16 [b][j][c] (XCD-local grid)
  attn_mfma_kernel<<<dim3(512), 256, 0, stream>>>(qT, kT, vN, aT);
  // 6. Output projection: D[o][j] = Wout @ aT^T + bias + residual
  gemm_rr<2><<<dim3(8, 4, 8), 256, 0, stream>>>(wbo, 0, aT, (size_t)HW * C,
                                                b_out, nullptr, nullptr, x, out);
}